// Round 1
// baseline (318.029 us; speedup 1.0000x reference)
//
#include <hip/hip_runtime.h>

#define CH 256
#define HH 128
#define WW 128
#define HW (HH * WW)

// One block per (b, c) image. 128 threads (2 waves).
// Single 64 KiB fp32 LDS plane with per-row rotation swizzle:
//   element (r, w) lives at  r*128 + ((w + r) & 127)
// -> row-parallel (lane-per-row, fixed w) and column-parallel (lane-per-col,
//    fixed h) accesses are both exactly 2-way bank aliased (free on gfx950).
//
// Phases:
//   0. global x -> LDS (coalesced float4)
//   H. thread-per-row, IN PLACE: forward overwrite with lr state, then
//      backward pass inverts the recurrence (x = (lr_w - d0*lr_{w-1})/c0),
//      computes rl, overwrites with m0*lr + m1*rl.
//   V. thread-per-column: tb re-reads x from GLOBAL (coalesced, L2/L3-hot),
//      LDS += m2*tb; bt re-reads x backward, fuses final add + coalesced
//      global store of m0*lr + m1*rl + m2*tb + m3*bt.
__global__ __launch_bounds__(128) void dscan_kernel(
    const float* __restrict__ x,
    const float* __restrict__ decay_logits,
    const float* __restrict__ mix_logits,
    const float* __restrict__ input_scale,
    float* __restrict__ out)
{
    __shared__ float xs[HW];  // exactly 64 KiB

    const int img = blockIdx.x;      // 0..2047  (b*256 + c)
    const int c   = img & (CH - 1);
    const int tid = threadIdx.x;

    // ---- per-channel params (block-uniform; 12 tiny cached loads) ----
    const float dl0 = decay_logits[0 * CH + c];
    const float dl1 = decay_logits[1 * CH + c];
    const float dl2 = decay_logits[2 * CH + c];
    const float dl3 = decay_logits[3 * CH + c];
    const float ml0 = mix_logits[0 * CH + c];
    const float ml1 = mix_logits[1 * CH + c];
    const float ml2 = mix_logits[2 * CH + c];
    const float ml3 = mix_logits[3 * CH + c];
    const float il0 = input_scale[0 * CH + c];
    const float il1 = input_scale[1 * CH + c];
    const float il2 = input_scale[2 * CH + c];
    const float il3 = input_scale[3 * CH + c];

    const float d0 = fminf(fmaxf(1.0f / (1.0f + expf(-dl0)), 0.05f), 0.995f);
    const float d1 = fminf(fmaxf(1.0f / (1.0f + expf(-dl1)), 0.05f), 0.995f);
    const float d2 = fminf(fmaxf(1.0f / (1.0f + expf(-dl2)), 0.05f), 0.995f);
    const float d3 = fminf(fmaxf(1.0f / (1.0f + expf(-dl3)), 0.05f), 0.995f);

    const float mmax = fmaxf(fmaxf(ml0, ml1), fmaxf(ml2, ml3));
    const float e0 = expf(ml0 - mmax);
    const float e1 = expf(ml1 - mmax);
    const float e2 = expf(ml2 - mmax);
    const float e3 = expf(ml3 - mmax);
    const float einv = 1.0f / (e0 + e1 + e2 + e3);
    const float m0 = e0 * einv, m1 = e1 * einv, m2 = e2 * einv, m3 = e3 * einv;

    const float sc0 = 1.0f + tanhf(il0);
    const float sc1 = 1.0f + tanhf(il1);
    const float sc2 = 1.0f + tanhf(il2);
    const float sc3 = 1.0f + tanhf(il3);

    const float c0 = (1.0f - d0) * sc0;   // s = d*s + c*x
    const float c1 = (1.0f - d1) * sc1;
    const float c2 = (1.0f - d2) * sc2;
    const float c3 = (1.0f - d3) * sc3;
    const float invc0 = 1.0f / c0;

    const float* __restrict__ xg = x + (size_t)img * HW;
    float* __restrict__ og = out + (size_t)img * HW;

    // ---- Phase 0: load tile (coalesced float4), rotated LDS stores ----
    {
        const float4* __restrict__ xg4 = (const float4*)xg;
#pragma unroll 4
        for (int i = 0; i < 32; ++i) {
            const int idx4 = tid + (i << 7);       // coalesced across lanes
            const float4 v = xg4[idx4];
            const int flat = idx4 << 2;
            const int r = flat >> 7;
            const int w = flat & 127;
            const int rb = r << 7;
            xs[rb + ((w + 0 + r) & 127)] = v.x;
            xs[rb + ((w + 1 + r) & 127)] = v.y;
            xs[rb + ((w + 2 + r) & 127)] = v.z;
            xs[rb + ((w + 3 + r) & 127)] = v.w;
        }
    }
    __syncthreads();

    // ---- Phase H: thread-per-row, in place ----
    {
        const int r = tid;
        const int rb = r << 7;

        // forward: overwrite with lr scan state
        float s = 0.0f;
#pragma unroll 8
        for (int w = 0; w < 128; ++w) {
            const int a = rb + ((w + r) & 127);
            const float xv = xs[a];
            s = fmaf(d0, s, c0 * xv);
            xs[a] = s;
        }

        // backward: invert lr to recover x, compute rl, write m0*lr + m1*rl
        float rls = 0.0f;
        float cur = xs[rb + ((127 + r) & 127)];   // lr_127
#pragma unroll 8
        for (int w = 127; w > 0; --w) {
            const float prev = xs[rb + ((w - 1 + r) & 127)];  // lr_{w-1}
            const float xv = (cur - d0 * prev) * invc0;       // recovered x_w
            rls = fmaf(d1, rls, c1 * xv);
            xs[rb + ((w + r) & 127)] = fmaf(m0, cur, m1 * rls);
            cur = prev;
        }
        {   // w == 0 : lr_{-1} = 0
            const float xv = cur * invc0;
            rls = fmaf(d1, rls, c1 * xv);
            xs[rb + (r & 127)] = fmaf(m0, cur, m1 * rls);
        }
    }
    __syncthreads();

    // ---- Phase V: thread-per-column, x re-read from global (coalesced) ----
    {
        const int t = tid;

        // top -> bottom: LDS += m2 * tb
        float s = 0.0f;
#pragma unroll 8
        for (int h = 0; h < 128; ++h) {
            const float xv = xg[(h << 7) + t];
            s = fmaf(d2, s, c2 * xv);
            const int a = (h << 7) + ((t + h) & 127);
            xs[a] += m2 * s;
        }

        // bottom -> top: fuse final add + coalesced global store
        s = 0.0f;
#pragma unroll 8
        for (int h = 127; h >= 0; --h) {
            const float xv = xg[(h << 7) + t];
            s = fmaf(d3, s, c3 * xv);
            const int a = (h << 7) + ((t + h) & 127);
            og[(h << 7) + t] = xs[a] + m3 * s;
        }
    }
}

extern "C" void kernel_launch(void* const* d_in, const int* in_sizes, int n_in,
                              void* d_out, int out_size, void* d_ws, size_t ws_size,
                              hipStream_t stream) {
    const float* x  = (const float*)d_in[0];
    const float* dl = (const float*)d_in[1];
    const float* ml = (const float*)d_in[2];
    const float* is = (const float*)d_in[3];
    float* out = (float*)d_out;

    dim3 grid(2048), block(128);
    hipLaunchKernelGGL(dscan_kernel, grid, block, 0, stream, x, dl, ml, is, out);
}

// Round 2
// 260.652 us; speedup vs baseline: 1.2201x; 1.2201x over previous
//
#include <hip/hip_runtime.h>

#define CH 256
#define HH 128
#define WW 128
#define HW (HH * WW)
#define SEGH 16   // rows per vertical segment
#define NSEG 8    // 128 / SEGH

// One block per (b,c) image. 1024 threads (16 waves). 64 KiB LDS plane.
//
// Phase V1: thread = (col, seg). Stream 16 x's from global (coalesced),
//           compute tb-segment exit state B2 and bt-segment exit state B3
//           (bt streams forward as sum d3^i * c3 * x_i). Store to LDS
//           scratch (aliased into the plane — plane not yet in use).
// Fixup:    each thread composes its incoming states Sin/Tin from the
//           <=7 other segment summaries of its column (registers).
// Phase H:  wave-parallel linear-recurrence scan. Each half-wave (width-32
//           shuffles) owns one row: float4 load (L2-hot), local compose of
//           4 elems, 5-step Kogge-Stone over (A,B) operators for lr
//           (shfl_up) and rl (shfl_down), write m0*lr + m1*rl to plane.
// Phase V2: re-stream x (L2-hot) into regs, apply tb with Sin, bt with Tin,
//           fuse out = plane + m2*tb + m3*bt, coalesced store.
__global__ __launch_bounds__(1024, 4) void dscan_kernel(
    const float* __restrict__ x,
    const float* __restrict__ decay_logits,
    const float* __restrict__ mix_logits,
    const float* __restrict__ input_scale,
    float* __restrict__ out)
{
    __shared__ float xs[HW];  // 64 KiB

    const int img  = blockIdx.x;          // b*256 + c
    const int c    = img & (CH - 1);
    const int tid  = threadIdx.x;
    const int lane = tid & 63;
    const int wv   = tid >> 6;            // 0..15

    // ---- per-channel params (block-uniform) ----
    const float dl0 = decay_logits[0 * CH + c];
    const float dl1 = decay_logits[1 * CH + c];
    const float dl2 = decay_logits[2 * CH + c];
    const float dl3 = decay_logits[3 * CH + c];
    const float ml0 = mix_logits[0 * CH + c];
    const float ml1 = mix_logits[1 * CH + c];
    const float ml2 = mix_logits[2 * CH + c];
    const float ml3 = mix_logits[3 * CH + c];
    const float il0 = input_scale[0 * CH + c];
    const float il1 = input_scale[1 * CH + c];
    const float il2 = input_scale[2 * CH + c];
    const float il3 = input_scale[3 * CH + c];

    const float d0 = fminf(fmaxf(1.0f / (1.0f + expf(-dl0)), 0.05f), 0.995f);
    const float d1 = fminf(fmaxf(1.0f / (1.0f + expf(-dl1)), 0.05f), 0.995f);
    const float d2 = fminf(fmaxf(1.0f / (1.0f + expf(-dl2)), 0.05f), 0.995f);
    const float d3 = fminf(fmaxf(1.0f / (1.0f + expf(-dl3)), 0.05f), 0.995f);

    const float mmax = fmaxf(fmaxf(ml0, ml1), fmaxf(ml2, ml3));
    const float e0 = expf(ml0 - mmax);
    const float e1 = expf(ml1 - mmax);
    const float e2 = expf(ml2 - mmax);
    const float e3 = expf(ml3 - mmax);
    const float einv = 1.0f / (e0 + e1 + e2 + e3);
    const float m0 = e0 * einv, m1 = e1 * einv, m2 = e2 * einv, m3 = e3 * einv;

    const float sc0 = 1.0f + tanhf(il0);
    const float sc1 = 1.0f + tanhf(il1);
    const float sc2 = 1.0f + tanhf(il2);
    const float sc3 = 1.0f + tanhf(il3);

    const float c0 = (1.0f - d0) * sc0;   // s = d*s + c*x
    const float c1 = (1.0f - d1) * sc1;
    const float c2 = (1.0f - d2) * sc2;
    const float c3 = (1.0f - d3) * sc3;

    const float d0p4 = (d0 * d0) * (d0 * d0);
    const float d1p4 = (d1 * d1) * (d1 * d1);
    float t2 = d2 * d2; t2 = t2 * t2; t2 = t2 * t2; const float d2p16 = t2 * t2;
    float t3 = d3 * d3; t3 = t3 * t3; t3 = t3 * t3; const float d3p16 = t3 * t3;

    const float* __restrict__ xg = x + (size_t)img * HW;
    float* __restrict__ og = out + (size_t)img * HW;

    // ---- Phase V1: segment summaries ----
    const int col = tid & (WW - 1);       // 0..127
    const int seg = tid >> 7;             // 0..7
    const float* __restrict__ xcol = xg + seg * SEGH * WW + col;

    {
        float b2 = 0.0f, b3 = 0.0f, pw = c3;
#pragma unroll
        for (int i = 0; i < SEGH; ++i) {
            const float xv = xcol[i * WW];
            b2 = fmaf(d2, b2, c2 * xv);   // forward local scan, exit state
            b3 = fmaf(pw, xv, b3);        // reverse local scan exit = sum d3^i*c3*x_i
            pw *= d3;
        }
        xs[tid]        = b2;              // scratch, aliases plane rows 0..7
        xs[1024 + tid] = b3;              // scratch, aliases plane rows 8..15
    }
    __syncthreads();

    // ---- Fixup: incoming states per (col, seg) ----
    float Sin = 0.0f;
    for (int j = 0; j < seg; ++j)
        Sin = fmaf(d2p16, Sin, xs[j * WW + col]);
    float Tin = 0.0f;
    for (int j = NSEG - 1; j > seg; --j)
        Tin = fmaf(d3p16, Tin, xs[1024 + j * WW + col]);
    __syncthreads();   // scratch reads done before H overwrites plane

    // ---- Phase H: wave-parallel row scans (half-wave per row) ----
    {
        const int sl   = lane & 31;       // lane within 32-group
        const int half = lane >> 5;       // which row of the pair
#pragma unroll
        for (int it = 0; it < 4; ++it) {
            const int r = (((it << 4) + wv) << 1) + half;   // 0..127
            const float4 xv4 = *(const float4*)(xg + r * WW + (sl << 2));

            // local composed operator over 4 elems: lr (forward)
            float bL = c0 * xv4.x;
            bL = fmaf(d0, bL, c0 * xv4.y);
            bL = fmaf(d0, bL, c0 * xv4.z);
            bL = fmaf(d0, bL, c0 * xv4.w);
            float aL = d0p4;
            // rl (reverse)
            float bR = c1 * xv4.w;
            bR = fmaf(d1, bR, c1 * xv4.z);
            bR = fmaf(d1, bR, c1 * xv4.y);
            bR = fmaf(d1, bR, c1 * xv4.x);
            float aR = d1p4;

            // Kogge-Stone inclusive scans over 32 lanes (width-32 groups)
#pragma unroll
            for (int off = 1; off < 32; off <<= 1) {
                const float aU = __shfl_up(aL, (unsigned)off, 32);
                const float bU = __shfl_up(bL, (unsigned)off, 32);
                if (sl >= off) { bL = fmaf(aL, bU, bL); aL *= aU; }
                const float aD = __shfl_down(aR, (unsigned)off, 32);
                const float bD = __shfl_down(bR, (unsigned)off, 32);
                if (sl < 32 - off) { bR = fmaf(aR, bD, bR); aR *= aD; }
            }
            // exclusive incoming states
            float EL = __shfl_up(bL, 1u, 32);
            if (sl == 0) EL = 0.0f;
            float ER = __shfl_down(bR, 1u, 32);
            if (sl == 31) ER = 0.0f;

            // recompute elementwise (exact)
            const float l0 = fmaf(d0, EL, c0 * xv4.x);
            const float l1 = fmaf(d0, l0, c0 * xv4.y);
            const float l2 = fmaf(d0, l1, c0 * xv4.z);
            const float l3 = fmaf(d0, l2, c0 * xv4.w);
            const float r3 = fmaf(d1, ER, c1 * xv4.w);
            const float r2 = fmaf(d1, r3, c1 * xv4.z);
            const float r1 = fmaf(d1, r2, c1 * xv4.y);
            const float r0 = fmaf(d1, r1, c1 * xv4.x);

            float4 o4;
            o4.x = fmaf(m0, l0, m1 * r0);
            o4.y = fmaf(m0, l1, m1 * r1);
            o4.z = fmaf(m0, l2, m1 * r2);
            o4.w = fmaf(m0, l3, m1 * r3);
            *(float4*)(xs + r * WW + (sl << 2)) = o4;
        }
    }
    __syncthreads();

    // ---- Phase V2: apply vertical scans + fused store ----
    {
        float xv[SEGH], tb[SEGH];
        float s = Sin;
#pragma unroll
        for (int i = 0; i < SEGH; ++i) {
            const float v = xcol[i * WW];       // L2-hot re-read
            xv[i] = v;
            s = fmaf(d2, s, c2 * v);
            tb[i] = s;
        }
        float t = Tin;
        float* __restrict__ ocol = og + seg * SEGH * WW + col;
        const float* __restrict__ pcol = xs + seg * SEGH * WW + col;
#pragma unroll
        for (int i = SEGH - 1; i >= 0; --i) {
            t = fmaf(d3, t, c3 * xv[i]);
            const float hres = pcol[i * WW];
            ocol[i * WW] = fmaf(m2, tb[i], fmaf(m3, t, hres));
        }
    }
}

extern "C" void kernel_launch(void* const* d_in, const int* in_sizes, int n_in,
                              void* d_out, int out_size, void* d_ws, size_t ws_size,
                              hipStream_t stream) {
    const float* x  = (const float*)d_in[0];
    const float* dl = (const float*)d_in[1];
    const float* ml = (const float*)d_in[2];
    const float* is = (const float*)d_in[3];
    float* out = (float*)d_out;

    dim3 grid(2048), block(1024);
    hipLaunchKernelGGL(dscan_kernel, grid, block, 0, stream, x, dl, ml, is, out);
}

// Round 3
// 245.377 us; speedup vs baseline: 1.2961x; 1.0623x over previous
//
#include <hip/hip_runtime.h>

#define CH 256
#define HH 128
#define WW 128
#define HW (HH * WW)
#define SEGH 16   // rows per vertical segment
#define NSEG 8    // 128 / SEGH

// One block per (b,c) image. 1024 threads (16 waves).
// Dynamic LDS: 64 KiB result plane + 8 KiB segment-summary scratch = 72 KiB
// (2 blocks/CU: 144 <= 160 KiB).
//
// Single-barrier structure:
//   Phase H  (pre-barrier): cold float4 row-major read of x. Half-wave
//            (32 lanes) per row, 4 rows/thread. Constant-decay Kogge-Stone:
//            since decay is uniform per channel, the scan operator's A-part
//            is the known power d^(4*off) -> 1 shuffle + 1 fma + 1 select
//            per KS step per direction. Writes m0*lr + m1*rl to plane.
//   Phase V1 (pre-barrier): thread=(col,seg), 16 L2-warm column loads,
//            computes tb segment exit state b2 and bt segment exit state b3,
//            writes to scratch.
//   --- one __syncthreads ---
//   Fixup:   compose incoming states Sin/Tin from <=7 summaries (scratch).
//   Phase V2: re-stream x (L2-warm), apply tb with Sin / bt with Tin,
//            out = plane + m2*tb + m3*bt, coalesced store.
__global__ __launch_bounds__(1024, 4) void dscan_kernel(
    const float* __restrict__ x,
    const float* __restrict__ decay_logits,
    const float* __restrict__ mix_logits,
    const float* __restrict__ input_scale,
    float* __restrict__ out)
{
    extern __shared__ float smem[];
    float* __restrict__ xs  = smem;           // 16384 floats: result plane
    float* __restrict__ scr = smem + HW;      // 2048 floats: b2 (1024) + b3 (1024)

    const int img  = blockIdx.x;              // b*256 + c
    const int c    = img & (CH - 1);
    const int tid  = threadIdx.x;
    const int lane = tid & 63;
    const int wv   = tid >> 6;                // 0..15

    // ---- per-channel params (block-uniform) ----
    const float dl0 = decay_logits[0 * CH + c];
    const float dl1 = decay_logits[1 * CH + c];
    const float dl2 = decay_logits[2 * CH + c];
    const float dl3 = decay_logits[3 * CH + c];
    const float ml0 = mix_logits[0 * CH + c];
    const float ml1 = mix_logits[1 * CH + c];
    const float ml2 = mix_logits[2 * CH + c];
    const float ml3 = mix_logits[3 * CH + c];
    const float il0 = input_scale[0 * CH + c];
    const float il1 = input_scale[1 * CH + c];
    const float il2 = input_scale[2 * CH + c];
    const float il3 = input_scale[3 * CH + c];

    const float d0 = fminf(fmaxf(1.0f / (1.0f + expf(-dl0)), 0.05f), 0.995f);
    const float d1 = fminf(fmaxf(1.0f / (1.0f + expf(-dl1)), 0.05f), 0.995f);
    const float d2 = fminf(fmaxf(1.0f / (1.0f + expf(-dl2)), 0.05f), 0.995f);
    const float d3 = fminf(fmaxf(1.0f / (1.0f + expf(-dl3)), 0.05f), 0.995f);

    const float mmax = fmaxf(fmaxf(ml0, ml1), fmaxf(ml2, ml3));
    const float e0 = expf(ml0 - mmax);
    const float e1 = expf(ml1 - mmax);
    const float e2 = expf(ml2 - mmax);
    const float e3 = expf(ml3 - mmax);
    const float einv = 1.0f / (e0 + e1 + e2 + e3);
    const float m0 = e0 * einv, m1 = e1 * einv, m2 = e2 * einv, m3 = e3 * einv;

    const float sc0 = 1.0f + tanhf(il0);
    const float sc1 = 1.0f + tanhf(il1);
    const float sc2 = 1.0f + tanhf(il2);
    const float sc3 = 1.0f + tanhf(il3);

    const float c0 = (1.0f - d0) * sc0;   // s = d*s + c*x
    const float c1 = (1.0f - d1) * sc1;
    const float c2 = (1.0f - d2) * sc2;
    const float c3 = (1.0f - d3) * sc3;

    // powers of decay for KS steps: q[k] = d^(4*2^k)
    const float d0p4 = (d0 * d0) * (d0 * d0);
    const float d1p4 = (d1 * d1) * (d1 * d1);
    float q0[5], q1[5];
    q0[0] = d0p4; q1[0] = d1p4;
#pragma unroll
    for (int k = 1; k < 5; ++k) { q0[k] = q0[k-1] * q0[k-1]; q1[k] = q1[k-1] * q1[k-1]; }

    float t2 = d2 * d2; t2 = t2 * t2; t2 = t2 * t2; const float d2p16 = t2 * t2;
    float t3 = d3 * d3; t3 = t3 * t3; t3 = t3 * t3; const float d3p16 = t3 * t3;

    const float* __restrict__ xg = x + (size_t)img * HW;
    float* __restrict__ og = out + (size_t)img * HW;

    // ---- Phase H: cold float4 read, constant-decay KS row scans ----
    {
        const int sl   = lane & 31;       // lane within 32-group
        const int half = lane >> 5;       // which row of the pair
        const int rbase = (wv << 1) + half;

        float4 v[4];
#pragma unroll
        for (int it = 0; it < 4; ++it)
            v[it] = *(const float4*)(xg + ((it << 5) + rbase) * WW + (sl << 2));

#pragma unroll
        for (int it = 0; it < 4; ++it) {
            const int r = (it << 5) + rbase;
            const float4 xv4 = v[it];

            // local inclusive compose over the 4 elements
            float bL = c0 * xv4.x;
            bL = fmaf(d0, bL, c0 * xv4.y);
            bL = fmaf(d0, bL, c0 * xv4.z);
            bL = fmaf(d0, bL, c0 * xv4.w);
            float bR = c1 * xv4.w;
            bR = fmaf(d1, bR, c1 * xv4.z);
            bR = fmaf(d1, bR, c1 * xv4.y);
            bR = fmaf(d1, bR, c1 * xv4.x);

            // constant-decay Kogge-Stone over 32 lanes, both directions
#pragma unroll
            for (int k = 0; k < 5; ++k) {
                const int off = 1 << k;
                const float bU = __shfl_up(bL, (unsigned)off, 32);
                bL = fmaf(q0[k], (sl >= off) ? bU : 0.0f, bL);
                const float bD = __shfl_down(bR, (unsigned)off, 32);
                bR = fmaf(q1[k], (sl < 32 - off) ? bD : 0.0f, bR);
            }
            // exclusive incoming states
            float EL = __shfl_up(bL, 1u, 32);
            if (sl == 0) EL = 0.0f;
            float ER = __shfl_down(bR, 1u, 32);
            if (sl == 31) ER = 0.0f;

            // recompute elementwise (exact)
            const float l0 = fmaf(d0, EL, c0 * xv4.x);
            const float l1 = fmaf(d0, l0, c0 * xv4.y);
            const float l2 = fmaf(d0, l1, c0 * xv4.z);
            const float l3 = fmaf(d0, l2, c0 * xv4.w);
            const float r3 = fmaf(d1, ER, c1 * xv4.w);
            const float r2 = fmaf(d1, r3, c1 * xv4.z);
            const float r1 = fmaf(d1, r2, c1 * xv4.y);
            const float r0 = fmaf(d1, r1, c1 * xv4.x);

            float4 o4;
            o4.x = fmaf(m0, l0, m1 * r0);
            o4.y = fmaf(m0, l1, m1 * r1);
            o4.z = fmaf(m0, l2, m1 * r2);
            o4.w = fmaf(m0, l3, m1 * r3);
            *(float4*)(xs + r * WW + (sl << 2)) = o4;
        }
    }

    // ---- Phase V1: segment summaries (L2-warm reads) ----
    const int col = tid & (WW - 1);       // 0..127
    const int seg = tid >> 7;             // 0..7
    const float* __restrict__ xcol = xg + seg * SEGH * WW + col;
    {
        float b2 = 0.0f, b3 = 0.0f, pw = c3;
#pragma unroll
        for (int i = 0; i < SEGH; ++i) {
            const float xv = xcol[i * WW];
            b2 = fmaf(d2, b2, c2 * xv);   // forward local scan exit state
            b3 = fmaf(pw, xv, b3);        // reverse local scan exit = sum d3^i*c3*x_i
            pw *= d3;
        }
        scr[tid]        = b2;
        scr[1024 + tid] = b3;
    }

    __syncthreads();   // the ONE barrier

    // ---- Fixup: incoming states per (col, seg) ----
    float Sin = 0.0f;
    for (int j = 0; j < seg; ++j)
        Sin = fmaf(d2p16, Sin, scr[j * WW + col]);
    float Tin = 0.0f;
    for (int j = NSEG - 1; j > seg; --j)
        Tin = fmaf(d3p16, Tin, scr[1024 + j * WW + col]);

    // ---- Phase V2: apply vertical scans + fused store ----
    {
        float xv[SEGH], tb[SEGH];
        float s = Sin;
#pragma unroll
        for (int i = 0; i < SEGH; ++i) {
            const float v = xcol[i * WW];       // L2-warm re-read
            xv[i] = v;
            s = fmaf(d2, s, c2 * v);
            tb[i] = s;
        }
        float t = Tin;
        float* __restrict__ ocol = og + seg * SEGH * WW + col;
        const float* __restrict__ pcol = xs + seg * SEGH * WW + col;
#pragma unroll
        for (int i = SEGH - 1; i >= 0; --i) {
            t = fmaf(d3, t, c3 * xv[i]);
            const float hres = pcol[i * WW];
            ocol[i * WW] = fmaf(m2, tb[i], fmaf(m3, t, hres));
        }
    }
}

extern "C" void kernel_launch(void* const* d_in, const int* in_sizes, int n_in,
                              void* d_out, int out_size, void* d_ws, size_t ws_size,
                              hipStream_t stream) {
    const float* x  = (const float*)d_in[0];
    const float* dl = (const float*)d_in[1];
    const float* ml = (const float*)d_in[2];
    const float* is = (const float*)d_in[3];
    float* out = (float*)d_out;

    const size_t lds_bytes = (size_t)(HW + 2048) * sizeof(float);   // 73728

    static bool attr_set = false;   // idempotent host-side attribute; value never changes
    if (!attr_set) {
        (void)hipFuncSetAttribute((const void*)dscan_kernel,
                                  hipFuncAttributeMaxDynamicSharedMemorySize,
                                  (int)lds_bytes);
        attr_set = true;
    }

    dim3 grid(2048), block(1024);
    hipLaunchKernelGGL(dscan_kernel, grid, block, lds_bytes, stream, x, dl, ml, is, out);
}